// Round 8
// baseline (240.427 us; speedup 1.0000x reference)
//
#include <hip/hip_runtime.h>

// STKBranch double-softmax attention, f16-MFMA 2-pass, R18:
//   - KEY-SPLIT 1024-thread blocks: 16 waves = 2 key-groups x 8 waves.
//     Group g handles keys [g*1024,(g+1)*1024) for the SAME 128 q-rows.
//     Grid stays 512 -> 2 blocks/CU = 32 waves/CU (hw max), NO duplicated
//     staging (each key staged once per block per pass, as before), and
//     per-wave tile count halves (16 vs 32) -> half the barriers per wave.
//   - group-private Ks/Vt double-buffers (73728 B) + 1 KB sred scratch ->
//     dynamic LDS 74752 B, 2 blocks/CU = 149.5 KB <= 160 KB.
//   - s1 merged across groups once after pass 1 (LDS exchange); O/Oe partials
//     merged once at the end through the then-dead Ks/Vt region.
//   - __launch_bounds__(1024,8) pins VGPR<=64 (R17 sits at exactly 64).
//   - keeps R17: swapped QK^T -> P in regs as PV B-frag; Vt permuted columns
//     c(key)=((key>>2)&3)*16+(key>>4)*4+(key&3) -> PV reads are b128; pair
//     interleave softmax->PV; prefetch-early; ones-MFMA l2; setprio.
// Math: L = scale*q@k^T ; w = softmax(2L) ; attn = softmax(L*w) ; out = attn@v
// |L| <= ~7 -> no max-subtraction. B=4 H=8 N=2048 D=64 fp32 io.

typedef _Float16 f16;
typedef f16 f16x8 __attribute__((ext_vector_type(8)));
typedef f16 f16x4 __attribute__((ext_vector_type(4)));
typedef float f32x4 __attribute__((ext_vector_type(4)));

#define MFMA32(a, b, c) __builtin_amdgcn_mfma_f32_16x16x32_f16((a), (b), (c), 0, 0, 0)
#define MFMA16(a, b, c) __builtin_amdgcn_mfma_f32_16x16x16f16((a), (b), (c), 0, 0, 0)
#define EXP2(x) __builtin_amdgcn_exp2f(x)   // v_exp_f32: D = 2^S0

#define N_CTX 2048
#define DH 64
#define KT 64
#define NKT_G 16          // tiles per key-group (1024 keys / KT)
#define ROWS 128          // 8 waves x 16 q-rows (per group)
#define QS 72             // universal LDS row stride (f16): 144 B
#define KSB (KT * QS)     // 4608 f16 = one Ks (or Vt) buffer
// smem carve (f16 units): KsG0 dbuf | KsG1 dbuf | VtG0 dbuf | VtG1 dbuf | sred
#define SMEM_F16 (4 * 2 * KSB + 512)      // 37376 f16 = 74752 B

#define C2 2.885390081777927f    // 2*log2(e), folded into Q fragments

__device__ inline unsigned pk(float a, float b) {
    typedef __fp16 fp16x2_t __attribute__((ext_vector_type(2)));
    union { fp16x2_t v; unsigned u; } x;
    x.v = __builtin_amdgcn_cvt_pkrtz(a, b);
    return x.u;
}

__global__ __launch_bounds__(1024, 8)
void stk_attn_mfma(const float* __restrict__ qg, const float* __restrict__ kg,
                   const float* __restrict__ vglob, const float* __restrict__ sg,
                   float* __restrict__ og) {
    extern __shared__ f16 smem[];

    const int tid  = threadIdx.x;
    const int wv   = tid >> 6;        // 0..15
    const int grp  = wv >> 3;         // key-group 0/1
    const int wv7  = wv & 7;          // wave within group
    const int lane = tid & 63;
    const int l15  = lane & 15;
    const int q4   = lane >> 4;
    const int tg   = (wv7 << 6) | lane;  // tid within group, 0..511
    const int vp   = tg & 31;         // V staging: key pair (2vp, 2vp+1)
    const int vgr  = tg >> 5;         // V staging: d-quad (0..15)
    const int bh   = blockIdx.x & 31; // XCD swizzle: head h -> blocks h+32j -> XCD h%8
    const int q0   = (blockIdx.x >> 5) * ROWS;
    const float scale2 = sg[0] * C2;  // fold 2*log2e: acc = 2L*log2e

    const float* qb = qg + (size_t)bh * N_CTX * DH;
    const float* kb = kg + (size_t)bh * N_CTX * DH;
    const float* vb = vglob + (size_t)bh * N_CTX * DH;
    float*       ob = og + (size_t)bh * N_CTX * DH;
    // group-local key base
    const float* kbg = kb + (size_t)grp * (NKT_G * KT) * DH;
    const float* vbg = vb + (size_t)grp * (NKT_G * KT) * DH;

    // ---- Q fragments direct from global (no LDS): row q0 + wv7*16 + l15 ----
    // (both groups load the same Q rows; B operand of swapped QK^T)
    f16x8 aq[2];
    {
        const float* qrow = qb + (size_t)(q0 + wv7 * 16 + l15) * DH;
        #pragma unroll
        for (int kc = 0; kc < 2; ++kc) {
            float4 a0 = *(const float4*)&qrow[kc * 32 + q4 * 8];
            float4 a1 = *(const float4*)&qrow[kc * 32 + q4 * 8 + 4];
            union { f16x8 h; unsigned u[4]; } A;
            A.u[0] = pk(a0.x * scale2, a0.y * scale2);
            A.u[1] = pk(a0.z * scale2, a0.w * scale2);
            A.u[2] = pk(a1.x * scale2, a1.y * scale2);
            A.u[3] = pk(a1.z * scale2, a1.w * scale2);
            aq[kc] = A.h;
        }
    }

    // loop-invariant staging offsets (K): idx = it*512 + tg
    int kofs[2], gofs[2];
    #pragma unroll
    for (int it = 0; it < 2; ++it) {
        int idx = it * 512 + tg;
        gofs[it] = (idx >> 4) * DH + (idx & 15) * 4;   // global f32 offset within tile
        kofs[it] = (idx >> 4) * QS + (idx & 15) * 4;   // LDS f16 offset within buffer
    }
    // V staging permuted column base: keys (2vp, 2vp+1) -> columns (c2p, c2p+1)
    const int c2p = ((vp >> 1) & 3) * 16 + (vp >> 3) * 4 + (vp & 1) * 2;

    // group-private LDS bases (all ds offsets below are immediates)
    f16* const ksBase = smem + grp * (2 * KSB);
    f16* const vtBase = smem + 2 * (2 * KSB) + grp * (2 * KSB);
    float* const sred = (float*)(smem + 4 * (2 * KSB));   // 256 floats
    float* const obuf = (float*)smem;                     // reduce scratch (epilogue)

    f16* const ks_w  = ksBase;
    const f16* const ks_r = ksBase + l15 * QS + q4 * 8;   // A-frag of QK^T: K row l15
    f16* const vt_w  = vtBase + (vgr * 4) * QS + c2p;
    const f16* const vt_r = vtBase + l15 * QS + q4 * 16;  // PV A-frags: 16 contiguous f16

    // =============== PASS 1: s1 = sum_k exp(2L) per q-row (group keys) ===============
    float s1 = 0.f;
    float4 kr[2];
    #pragma unroll
    for (int it = 0; it < 2; ++it)
        kr[it] = *(const float4*)&kbg[gofs[it]];
    #pragma unroll
    for (int it = 0; it < 2; ++it)
        *(uint2*)&ks_w[kofs[it]] =
            make_uint2(pk(kr[it].x, kr[it].y), pk(kr[it].z, kr[it].w));
    #pragma unroll
    for (int it = 0; it < 2; ++it)
        kr[it] = *(const float4*)&kbg[KT * DH + gofs[it]];
    __syncthreads();

    for (int kt = 0; kt < NKT_G; ++kt) {
        const int cur = (kt & 1) * KSB, nxt = KSB - cur;
        #pragma unroll
        for (int it = 0; it < 2; ++it)
            *(uint2*)&ks_w[nxt + kofs[it]] =
                make_uint2(pk(kr[it].x, kr[it].y), pk(kr[it].z, kr[it].w));
        {
            int tn = (kt + 2 < NKT_G) ? kt + 2 : NKT_G - 1;
            #pragma unroll
            for (int it = 0; it < 2; ++it)
                kr[it] = *(const float4*)&kbg[(size_t)tn * KT * DH + gofs[it]];
        }
        __builtin_amdgcn_s_setprio(1);
        #pragma unroll
        for (int kgi = 0; kgi < 4; ++kgi) {
            f16x8 b0 = *(const f16x8*)&ks_r[cur + kgi * 16 * QS];
            f16x8 b1 = *(const f16x8*)&ks_r[cur + kgi * 16 * QS + 32];
            f32x4 acc = {0.f, 0.f, 0.f, 0.f};
            acc = MFMA32(b0, aq[0], acc);   // swapped: C[key][q], lane q = l15
            acc = MFMA32(b1, aq[1], acc);
            s1 += (EXP2(acc[0]) + EXP2(acc[1])) + (EXP2(acc[2]) + EXP2(acc[3]));
        }
        __builtin_amdgcn_s_setprio(0);
        __syncthreads();
    }
    // reduce across q4 partitions, then across key-groups via sred
    s1 += __shfl_xor(s1, 16, 64);
    s1 += __shfl_xor(s1, 32, 64);
    if (lane < 16) sred[(grp << 7) + (wv7 << 4) + lane] = s1;
    __syncthreads();
    s1 += sred[((grp ^ 1) << 7) + (wv7 << 4) + l15];
    const float inv1 = 0.5f / s1;    // e2 = exp2((acc*e1) * 0.5/s1)  [acc = 2L*log2e]

    // =============== PASS 2: e2, O^T += V^T P^T, l2 via ones-MFMA ===============
    f32x4 O[4];
    #pragma unroll
    for (int dt = 0; dt < 4; ++dt) O[dt] = (f32x4){0.f, 0.f, 0.f, 0.f};
    f32x4 Oe = {0.f, 0.f, 0.f, 0.f};   // Oe[r] = sum_k P[k][q=l15] (group partial)
    const f16x4 ones = {(f16)1.f, (f16)1.f, (f16)1.f, (f16)1.f};

    float4 vr0, vr2;  // V prefetch: keys (2vp, 2vp+1), d-quad vgr*4..+3
    // prologue: Ks[0]<-K(g,0), Vt[0]<-V(g,0); kr<-K(g,1), vr<-V(g,1)
    #pragma unroll
    for (int it = 0; it < 2; ++it)
        kr[it] = *(const float4*)&kbg[gofs[it]];
    #pragma unroll
    for (int it = 0; it < 2; ++it)
        *(uint2*)&ks_w[kofs[it]] =
            make_uint2(pk(kr[it].x, kr[it].y), pk(kr[it].z, kr[it].w));
    {
        const float* vs = vbg + ((size_t)2 * vp) * DH + vgr * 4;
        float4 a0 = *(const float4*)(vs);
        float4 b0 = *(const float4*)(vs + DH);
        #pragma unroll
        for (int j = 0; j < 4; ++j)
            *(unsigned*)&vt_w[j * QS] = pk(((const float*)&a0)[j], ((const float*)&b0)[j]);
        const float* vs1 = vbg + ((size_t)(KT + 2 * vp)) * DH + vgr * 4;
        vr0 = *(const float4*)(vs1);
        vr2 = *(const float4*)(vs1 + DH);
    }
    #pragma unroll
    for (int it = 0; it < 2; ++it)
        kr[it] = *(const float4*)&kbg[KT * DH + gofs[it]];
    __syncthreads();

    for (int kt = 0; kt < NKT_G; ++kt) {
        const int cur = (kt & 1) * KSB, nxt = KSB - cur;
        // stage next K/V tile into the other buffers (overlaps all compute below)
        #pragma unroll
        for (int it = 0; it < 2; ++it)
            *(uint2*)&ks_w[nxt + kofs[it]] =
                make_uint2(pk(kr[it].x, kr[it].y), pk(kr[it].z, kr[it].w));
        #pragma unroll
        for (int j = 0; j < 4; ++j)
            *(unsigned*)&vt_w[nxt + j * QS] =
                pk(((const float*)&vr0)[j], ((const float*)&vr2)[j]);
        // prefetch K(kt+2), V(kt+2) issued BEFORE compute (full block in flight)
        {
            int tn = (kt + 2 < NKT_G) ? kt + 2 : NKT_G - 1;
            #pragma unroll
            for (int it = 0; it < 2; ++it)
                kr[it] = *(const float4*)&kbg[(size_t)tn * KT * DH + gofs[it]];
            const float* vs = vbg + ((size_t)(tn * KT + 2 * vp)) * DH + vgr * 4;
            vr0 = *(const float4*)(vs);
            vr2 = *(const float4*)(vs + DH);
        }
        // per kgi-PAIR: softmax(2p), softmax(2p+1) -> PV(pair p) via b128 V-frags.
        __builtin_amdgcn_s_setprio(1);
        #pragma unroll
        for (int p = 0; p < 2; ++p) {
            f16x4 pfr[2];
            #pragma unroll
            for (int h = 0; h < 2; ++h) {
                const int kgi = p * 2 + h;
                f16x8 b0 = *(const f16x8*)&ks_r[cur + kgi * 16 * QS];
                f16x8 b1 = *(const f16x8*)&ks_r[cur + kgi * 16 * QS + 32];
                f32x4 acc = {0.f, 0.f, 0.f, 0.f};
                acc = MFMA32(b0, aq[0], acc);
                acc = MFMA32(b1, aq[1], acc);
                float e2r[4];
                #pragma unroll
                for (int r = 0; r < 4; ++r) {
                    float a  = acc[r];
                    float e1 = EXP2(a);
                    e2r[r] = EXP2((a * e1) * inv1);
                }
                union { f16x4 hh; unsigned u[2]; } P;
                P.u[0] = pk(e2r[0], e2r[1]);
                P.u[1] = pk(e2r[2], e2r[3]);
                pfr[h] = P.hh;
                Oe = MFMA16(ones, pfr[h], Oe);
            }
            // PV for kgi pair (2p, 2p+1): one b128 per dt covers both halves
            #pragma unroll
            for (int dt = 0; dt < 4; ++dt) {
                f16x8 av = *(const f16x8*)&vt_r[cur + dt * 16 * QS + p * 8];
                f16x4 alo = __builtin_shufflevector(av, av, 0, 1, 2, 3);
                f16x4 ahi = __builtin_shufflevector(av, av, 4, 5, 6, 7);
                O[dt] = MFMA16(alo, pfr[0], O[dt]);
                O[dt] = MFMA16(ahi, pfr[1], O[dt]);
            }
        }
        __builtin_amdgcn_s_setprio(0);
        __syncthreads();   // swap: protects Ks/Vt cur<->nxt for next iteration
    }

    // ---- cross-group merge of O/Oe, then finalize (group 0 writes) ----
    // Ks/Vt regions are dead now; obuf record = 20 f32/lane (16B-aligned).
    const int rec = tg * 20;
    if (grp) {
        #pragma unroll
        for (int dt = 0; dt < 4; ++dt)
            *(f32x4*)&obuf[rec + dt * 4] = O[dt];
        obuf[rec + 16] = Oe[0];
    }
    __syncthreads();
    if (!grp) {
        #pragma unroll
        for (int dt = 0; dt < 4; ++dt)
            O[dt] += *(const f32x4*)&obuf[rec + dt * 4];
        const float invl2 = 1.0f / (Oe[0] + obuf[rec + 16]);
        const size_t orow = (size_t)(q0 + wv7 * 16 + l15) * DH;
        #pragma unroll
        for (int dt = 0; dt < 4; ++dt) {
            float4 o;
            o.x = O[dt][0] * invl2;
            o.y = O[dt][1] * invl2;
            o.z = O[dt][2] * invl2;
            o.w = O[dt][3] * invl2;
            *(float4*)&ob[orow + dt * 16 + q4 * 4] = o;
        }
    }
}

extern "C" void kernel_launch(void* const* d_in, const int* in_sizes, int n_in,
                              void* d_out, int out_size, void* d_ws, size_t ws_size,
                              hipStream_t stream) {
    const float* q = (const float*)d_in[0];
    const float* k = (const float*)d_in[1];
    const float* v = (const float*)d_in[2];
    const float* s = (const float*)d_in[3];
    float* out = (float*)d_out;
    dim3 grid(32 * 16);   // bh = blockIdx&31 (XCD swizzle), q-tile = blockIdx>>5
    stk_attn_mfma<<<grid, 1024, SMEM_F16 * 2, stream>>>(q, k, v, s, out);
}

// Round 9
// 171.873 us; speedup vs baseline: 1.3989x; 1.3989x over previous
//
#include <hip/hip_runtime.h>

// STKBranch double-softmax attention, f16-MFMA 2-pass, R19:
//   R18 post-mortem: key-split 1024-thr blocks DID reach 83% occupancy but
//   spilled (VGPR capped 64, FETCH 253MB of scratch). Fix: remove staging
//   register/VALU pressure instead of abandoning the structure.
//   - PRE-PASS kernel (stream-ordered, same launch): converts K -> f16
//     ws layout [bh][key][d], and V -> f16 TRANSPOSED + column-PERMUTED
//     [bh][tile][d][c(key)], c(key)=((key>>2)&3)*16+((key>>4)&3)*4+(key&3)
//     (involution). 16 MB of d_ws. ~48MB traffic ~= 10us.
//   - main kernel staging per tile per thread: 1x f16x8 coalesced load +
//     1x ds_write_b128 (no pk, no float4 quads) -> ~8 fewer VGPRs, fits the
//     64-VGPR cap of __launch_bounds__(1024,8) -> 32 waves/CU, no spill.
//   - KEY-SPLIT kept from R18: 16 waves = 2 key-groups x 8; group g owns keys
//     [g*1024,(g+1)*1024) of the same 128 q-rows; s1 merged via LDS after
//     pass 1; O/l2 partials merged through dead Ks/Vt LDS at the end.
//   - compute/read paths byte-identical to PASSING R17: swapped QK^T, P in
//     regs as PV B-frag, b128 PV reads via permuted Vt cols, pair interleave,
//     ones-MFMA l2, setprio, QS=72 conflict-floor LDS.
// Math: L = scale*q@k^T ; w = softmax(2L) ; attn = softmax(L*w) ; out = attn@v
// |L| <= ~7 -> no max-subtraction. B=4 H=8 N=2048 D=64 fp32 io.

typedef _Float16 f16;
typedef f16 f16x8 __attribute__((ext_vector_type(8)));
typedef f16 f16x4 __attribute__((ext_vector_type(4)));
typedef float f32x4 __attribute__((ext_vector_type(4)));

#define MFMA32(a, b, c) __builtin_amdgcn_mfma_f32_16x16x32_f16((a), (b), (c), 0, 0, 0)
#define MFMA16(a, b, c) __builtin_amdgcn_mfma_f32_16x16x16f16((a), (b), (c), 0, 0, 0)
#define EXP2(x) __builtin_amdgcn_exp2f(x)   // v_exp_f32: D = 2^S0

#define N_CTX 2048
#define DH 64
#define KT 64
#define NKT_G 16          // tiles per key-group (1024 keys / KT)
#define ROWS 128          // 8 waves x 16 q-rows (per group)
#define QS 72             // LDS row stride (f16): 144 B (bank-floor, proven)
#define KSB (KT * QS)     // 4608 f16 = one Ks/Vt buffer (9216 B)
// smem carve (f16): KsG0 dbuf | KsG1 dbuf | VtG0 dbuf | VtG1 dbuf | sred(f32)
#define SMEM_BYTES (4 * 2 * KSB * 2 + 2048)   // 73728 + 2048 = 75776 B

#define C2 2.885390081777927f    // 2*log2(e), folded into Q fragments

__device__ inline unsigned pk(float a, float b) {
    typedef __fp16 fp16x2_t __attribute__((ext_vector_type(2)));
    union { fp16x2_t v; unsigned u; } x;
    x.v = __builtin_amdgcn_cvt_pkrtz(a, b);
    return x.u;
}

// ---------------- pre-pass: f32 K/V -> f16 workspace ----------------
// K: wsK[bh*131072 + key*64 + d]           (straight convert, coalesced)
// V: wsV[bh*131072 + t*4096 + d*64 + c]    (transpose + col-permute c(key))
__global__ __launch_bounds__(256)
void stk_prep(const float* __restrict__ kg, const float* __restrict__ vg,
              f16* __restrict__ wsK, f16* __restrict__ wsV) {
    const int bid = blockIdx.x, tid = threadIdx.x;
    if (bid < 2048) {   // K half: 524288 threads, one 16B chunk each
        int g = bid * 256 + tid;
        int bh = g >> 14, key = (g >> 3) & 2047, c = g & 7;
        const float* src = kg + (((size_t)bh * 2048 + key) << 6) + c * 8;
        float4 a = *(const float4*)src;
        float4 b = *(const float4*)(src + 4);
        uint4 o;
        o.x = pk(a.x, a.y); o.y = pk(a.z, a.w);
        o.z = pk(b.x, b.y); o.w = pk(b.z, b.w);
        *(uint4*)&wsK[(((size_t)bh * 2048 + key) << 6) + c * 8] = o;
    } else {            // V half: thread = (bh, t, c2, d), d innermost (coalesced reads)
        int g = (bid - 2048) * 256 + tid;
        int d = g & 63, c2 = (g >> 6) & 7, t = (g >> 9) & 31, bh = g >> 14;
        const float* vbase = vg + (((size_t)bh * 2048 + t * 64) << 6) + d;
        float vals[8];
        #pragma unroll
        for (int j = 0; j < 8; ++j) {
            int c = c2 * 8 + j;
            int key = ((c >> 2) & 3) * 16 + ((c >> 4) & 3) * 4 + (c & 3); // inv of c(key)
            vals[j] = vbase[key << 6];
        }
        uint4 o;
        o.x = pk(vals[0], vals[1]); o.y = pk(vals[2], vals[3]);
        o.z = pk(vals[4], vals[5]); o.w = pk(vals[6], vals[7]);
        *(uint4*)&wsV[((((size_t)bh * 32 + t) << 6) + d) * 64 + c2 * 8] = o;
    }
}

// ---------------- main kernel ----------------
__global__ __launch_bounds__(1024, 8)
void stk_attn_mfma(const float* __restrict__ qg, const f16* __restrict__ wsK,
                   const f16* __restrict__ wsV, const float* __restrict__ sg,
                   float* __restrict__ og) {
    extern __shared__ f16 smem[];

    const int tid  = threadIdx.x;
    const int wv   = tid >> 6;        // 0..15
    const int grp  = wv >> 3;         // key-group 0/1
    const int wv7  = wv & 7;          // wave within group
    const int lane = tid & 63;
    const int l15  = lane & 15;
    const int q4   = lane >> 4;
    const int tg   = (wv7 << 6) | lane;  // tid within group, 0..511
    const int bh   = blockIdx.x & 31; // XCD swizzle: head h -> blocks h+32j -> XCD h%8
    const int q0   = (blockIdx.x >> 5) * ROWS;
    const float scale2 = sg[0] * C2;  // fold 2*log2e: acc = 2L*log2e

    const float* qb = qg + (size_t)bh * N_CTX * DH;
    float*       ob = og + (size_t)bh * N_CTX * DH;
    const f16* wsKh = wsK + ((size_t)bh << 17);   // *131072
    const f16* wsVh = wsV + ((size_t)bh << 17);
    const int T0 = grp * NKT_G;       // group's first tile (of 32 per head)

    // ---- Q fragments direct from global: row q0 + wv7*16 + l15 ----
    f16x8 aq[2];
    {
        const float* qrow = qb + (size_t)(q0 + wv7 * 16 + l15) * DH;
        #pragma unroll
        for (int kc = 0; kc < 2; ++kc) {
            float4 a0 = *(const float4*)&qrow[kc * 32 + q4 * 8];
            float4 a1 = *(const float4*)&qrow[kc * 32 + q4 * 8 + 4];
            union { f16x8 h; unsigned u[4]; } A;
            A.u[0] = pk(a0.x * scale2, a0.y * scale2);
            A.u[1] = pk(a0.z * scale2, a0.w * scale2);
            A.u[2] = pk(a1.x * scale2, a1.y * scale2);
            A.u[3] = pk(a1.z * scale2, a1.w * scale2);
            aq[kc] = A.h;
        }
    }

    // group-private LDS bases
    f16* const ksBase = smem + grp * (2 * KSB);
    f16* const vtBase = smem + 2 * (2 * KSB) + grp * (2 * KSB);
    float* const sred = (float*)(smem + 4 * (2 * KSB));   // 512 floats
    float* const obuf = (float*)smem;                     // epilogue reuse

    const int sofs = tg * 8;                          // ws tile read offset (f16)
    const int wofs = (tg >> 3) * QS + (tg & 7) * 8;   // LDS b128 write offset

    f16* const ks_w = ksBase;
    const f16* const ks_r = ksBase + l15 * QS + q4 * 8;   // QK^T A-frag: K row l15
    f16* const vt_w = vtBase;
    const f16* const vt_r = vtBase + l15 * QS + q4 * 16;  // PV A-frags: 16 contiguous f16

    // =============== PASS 1: s1 = sum_k exp(2L) (group keys) ===============
    float s1 = 0.f;
    f16x8 krh;
    krh = *(const f16x8*)&wsKh[(size_t)T0 * 4096 + sofs];
    *(f16x8*)&ks_w[wofs] = krh;
    krh = *(const f16x8*)&wsKh[(size_t)(T0 + 1) * 4096 + sofs];
    __syncthreads();

    for (int kt = 0; kt < NKT_G; ++kt) {
        const int cur = (kt & 1) * KSB, nxt = KSB - cur;
        *(f16x8*)&ks_w[nxt + wofs] = krh;                 // tile kt+1
        { int tn = (kt + 2 < NKT_G) ? kt + 2 : NKT_G - 1; // prefetch kt+2
          krh = *(const f16x8*)&wsKh[(size_t)(T0 + tn) * 4096 + sofs]; }
        __builtin_amdgcn_s_setprio(1);
        #pragma unroll
        for (int kgi = 0; kgi < 4; ++kgi) {
            f16x8 b0 = *(const f16x8*)&ks_r[cur + kgi * 16 * QS];
            f16x8 b1 = *(const f16x8*)&ks_r[cur + kgi * 16 * QS + 32];
            f32x4 acc = {0.f, 0.f, 0.f, 0.f};
            acc = MFMA32(b0, aq[0], acc);   // swapped: C[key][q], lane q = l15
            acc = MFMA32(b1, aq[1], acc);
            s1 += (EXP2(acc[0]) + EXP2(acc[1])) + (EXP2(acc[2]) + EXP2(acc[3]));
        }
        __builtin_amdgcn_s_setprio(0);
        __syncthreads();
    }
    // reduce across q4 partitions, then across key-groups via sred
    s1 += __shfl_xor(s1, 16, 64);
    s1 += __shfl_xor(s1, 32, 64);
    if (lane < 16) sred[(grp << 7) + (wv7 << 4) + lane] = s1;
    __syncthreads();
    s1 += sred[((grp ^ 1) << 7) + (wv7 << 4) + l15];
    const float inv1 = 0.5f / s1;    // e2 = exp2((acc*e1) * 0.5/s1)  [acc = 2L*log2e]

    // =============== PASS 2: e2, O^T += V^T P^T, l2 via ones-MFMA ===============
    f32x4 O[4];
    #pragma unroll
    for (int dt = 0; dt < 4; ++dt) O[dt] = (f32x4){0.f, 0.f, 0.f, 0.f};
    f32x4 Oe = {0.f, 0.f, 0.f, 0.f};
    const f16x4 ones = {(f16)1.f, (f16)1.f, (f16)1.f, (f16)1.f};

    f16x8 vrh;
    krh = *(const f16x8*)&wsKh[(size_t)T0 * 4096 + sofs];
    vrh = *(const f16x8*)&wsVh[(size_t)T0 * 4096 + sofs];
    *(f16x8*)&ks_w[wofs] = krh;
    *(f16x8*)&vt_w[wofs] = vrh;
    krh = *(const f16x8*)&wsKh[(size_t)(T0 + 1) * 4096 + sofs];
    vrh = *(const f16x8*)&wsVh[(size_t)(T0 + 1) * 4096 + sofs];
    __syncthreads();

    for (int kt = 0; kt < NKT_G; ++kt) {
        const int cur = (kt & 1) * KSB, nxt = KSB - cur;
        *(f16x8*)&ks_w[nxt + wofs] = krh;
        *(f16x8*)&vt_w[nxt + wofs] = vrh;
        { int tn = (kt + 2 < NKT_G) ? kt + 2 : NKT_G - 1;
          krh = *(const f16x8*)&wsKh[(size_t)(T0 + tn) * 4096 + sofs];
          vrh = *(const f16x8*)&wsVh[(size_t)(T0 + tn) * 4096 + sofs]; }
        // per kgi-PAIR: softmax(2p), softmax(2p+1) -> PV(pair p) via b128 V-frags
        __builtin_amdgcn_s_setprio(1);
        #pragma unroll
        for (int p = 0; p < 2; ++p) {
            f16x4 pfr[2];
            #pragma unroll
            for (int h = 0; h < 2; ++h) {
                const int kgi = p * 2 + h;
                f16x8 b0 = *(const f16x8*)&ks_r[cur + kgi * 16 * QS];
                f16x8 b1 = *(const f16x8*)&ks_r[cur + kgi * 16 * QS + 32];
                f32x4 acc = {0.f, 0.f, 0.f, 0.f};
                acc = MFMA32(b0, aq[0], acc);
                acc = MFMA32(b1, aq[1], acc);
                float e2r[4];
                #pragma unroll
                for (int r = 0; r < 4; ++r) {
                    float a  = acc[r];
                    float e1 = EXP2(a);
                    e2r[r] = EXP2((a * e1) * inv1);
                }
                union { f16x4 hh; unsigned u[2]; } P;
                P.u[0] = pk(e2r[0], e2r[1]);
                P.u[1] = pk(e2r[2], e2r[3]);
                pfr[h] = P.hh;
                Oe = MFMA16(ones, pfr[h], Oe);
            }
            #pragma unroll
            for (int dt = 0; dt < 4; ++dt) {
                f16x8 av = *(const f16x8*)&vt_r[cur + dt * 16 * QS + p * 8];
                f16x4 alo = __builtin_shufflevector(av, av, 0, 1, 2, 3);
                f16x4 ahi = __builtin_shufflevector(av, av, 4, 5, 6, 7);
                O[dt] = MFMA16(alo, pfr[0], O[dt]);
                O[dt] = MFMA16(ahi, pfr[1], O[dt]);
            }
        }
        __builtin_amdgcn_s_setprio(0);
        __syncthreads();   // swap: protects Ks/Vt cur<->nxt
    }

    // ---- cross-group merge of O/Oe via dead Ks/Vt LDS; group 0 writes ----
    const int rec = tg * 20;   // 20 f32/thread, 16B-aligned (80 B)
    if (grp) {
        #pragma unroll
        for (int dt = 0; dt < 4; ++dt)
            *(f32x4*)&obuf[rec + dt * 4] = O[dt];
        obuf[rec + 16] = Oe[0];
    }
    __syncthreads();
    if (!grp) {
        #pragma unroll
        for (int dt = 0; dt < 4; ++dt)
            O[dt] += *(const f32x4*)&obuf[rec + dt * 4];
        const float invl2 = 1.0f / (Oe[0] + obuf[rec + 16]);
        const size_t orow = (size_t)(q0 + wv7 * 16 + l15) * DH;
        #pragma unroll
        for (int dt = 0; dt < 4; ++dt) {
            float4 o;
            o.x = O[dt][0] * invl2;
            o.y = O[dt][1] * invl2;
            o.z = O[dt][2] * invl2;
            o.w = O[dt][3] * invl2;
            *(float4*)&ob[orow + dt * 16 + q4 * 4] = o;
        }
    }
}

extern "C" void kernel_launch(void* const* d_in, const int* in_sizes, int n_in,
                              void* d_out, int out_size, void* d_ws, size_t ws_size,
                              hipStream_t stream) {
    const float* q = (const float*)d_in[0];
    const float* k = (const float*)d_in[1];
    const float* v = (const float*)d_in[2];
    const float* s = (const float*)d_in[3];
    float* out = (float*)d_out;
    f16* wsK = (f16*)d_ws;                       // 8 MB
    f16* wsV = wsK + (size_t)32 * N_CTX * DH;    // 8 MB
    stk_prep<<<dim3(4096), dim3(256), 0, stream>>>(k, v, wsK, wsV);
    dim3 grid(32 * 16);   // bh = blockIdx&31 (XCD swizzle), q-tile = blockIdx>>5
    stk_attn_mfma<<<grid, 1024, SMEM_BYTES, stream>>>(q, wsK, wsV, s, out);
}

// Round 10
// 170.253 us; speedup vs baseline: 1.4122x; 1.0095x over previous
//
#include <hip/hip_runtime.h>

// STKBranch double-softmax attention, f16-MFMA 2-pass, R20:
//   Base = R19 (key-split 1024-thr blocks, 2 groups x 8 waves, f16 ws staging;
//   main 90 us, occupancy 67%, no spill). Two independent fixes:
//   - PREP V-half via LDS TRANSPOSE: one block per (bh,tile); coalesced f32
//     reads, pk into lds[d][c(key)] (stride 72), barrier, coalesced 32B/thread
//     row writes. Old version wrote 16B at 128B stride (1/8 efficiency, ~12us);
//     now BW-floor ~8us for the whole prep.
//   - PASS-1 2-TILE STAGING through the idle Vt buffers: {Ks-dbuf, Vt-dbuf}
//     become two 2-tile super-buffers -> 128 keys staged per sync, 8 kgi per
//     compute region, pass-1 barriers 16 -> 8.
//   - everything else byte-identical to R19 (swapped QK^T, P in regs as PV
//     B-frag, permuted Vt cols -> b128 PV reads, pair interleave, ones-MFMA
//     l2, setprio, QS=72 floors, s1/O cross-group merges).
// Math: L = scale*q@k^T ; w = softmax(2L) ; attn = softmax(L*w) ; out = attn@v
// |L| <= ~7 -> no max-subtraction. B=4 H=8 N=2048 D=64 fp32 io.

typedef _Float16 f16;
typedef f16 f16x8 __attribute__((ext_vector_type(8)));
typedef f16 f16x4 __attribute__((ext_vector_type(4)));
typedef float f32x4 __attribute__((ext_vector_type(4)));

#define MFMA32(a, b, c) __builtin_amdgcn_mfma_f32_16x16x32_f16((a), (b), (c), 0, 0, 0)
#define MFMA16(a, b, c) __builtin_amdgcn_mfma_f32_16x16x16f16((a), (b), (c), 0, 0, 0)
#define EXP2(x) __builtin_amdgcn_exp2f(x)   // v_exp_f32: D = 2^S0

#define N_CTX 2048
#define DH 64
#define KT 64
#define NKT_G 16          // tiles per key-group (1024 keys / KT)
#define ROWS 128          // 8 waves x 16 q-rows (per group)
#define QS 72             // LDS row stride (f16): 144 B (bank-floor, proven)
#define KSB (KT * QS)     // 4608 f16 = one Ks/Vt buffer (9216 B)
// smem carve (f16): KsG0 dbuf | KsG1 dbuf | VtG0 dbuf | VtG1 dbuf | sred(f32)
#define SMEM_BYTES (4 * 2 * KSB * 2 + 2048)   // 73728 + 2048 = 75776 B

#define C2 2.885390081777927f    // 2*log2(e), folded into Q fragments

__device__ inline unsigned pk(float a, float b) {
    typedef __fp16 fp16x2_t __attribute__((ext_vector_type(2)));
    union { fp16x2_t v; unsigned u; } x;
    x.v = __builtin_amdgcn_cvt_pkrtz(a, b);
    return x.u;
}

// ---------------- pre-pass: f32 K/V -> f16 workspace ----------------
// K: wsK[bh*131072 + key*64 + d]           (straight convert, coalesced)
// V: wsV[bh*131072 + t*4096 + d*64 + c]    (LDS-transposed, col-permute c(key))
__global__ __launch_bounds__(256)
void stk_prep(const float* __restrict__ kg, const float* __restrict__ vg,
              f16* __restrict__ wsK, f16* __restrict__ wsV) {
    const int bid = blockIdx.x, tid = threadIdx.x;
    if (bid < 2048) {   // K half: straight convert, one 16B f16 chunk/thread
        int g = bid * 256 + tid;
        int bh = g >> 14, key = (g >> 3) & 2047, c = g & 7;
        const float* src = kg + (((size_t)bh * 2048 + key) << 6) + c * 8;
        float4 a = *(const float4*)src;
        float4 b = *(const float4*)(src + 4);
        uint4 o;
        o.x = pk(a.x, a.y); o.y = pk(a.z, a.w);
        o.z = pk(b.x, b.y); o.w = pk(b.z, b.w);
        *(uint4*)&wsK[(((size_t)bh * 2048 + key) << 6) + c * 8] = o;
    } else {            // V half: LDS transpose, one block per (bh, tile)
        __shared__ f16 lds[DH * QS];          // [d][c], stride 72
        const int bid2 = bid - 2048;          // 0..1023
        const int bh = bid2 >> 5, t = bid2 & 31;
        // read: pair p = tid>>3 (keys 2p,2p+1), dseg = tid&7 (d = dseg*8..+7)
        const int p = tid >> 3, dseg = tid & 7, d0 = dseg * 8;
        const int c0 = ((p >> 1) & 3) * 16 + ((p >> 3) & 3) * 4 + (p & 1) * 2;
        const float* base = vg + (((size_t)(bh * 2048 + t * 64 + 2 * p)) << 6) + d0;
        float4 a0 = *(const float4*)(base);
        float4 a1 = *(const float4*)(base + 4);
        float4 b0 = *(const float4*)(base + 64);
        float4 b1 = *(const float4*)(base + 68);
        #pragma unroll
        for (int j = 0; j < 4; ++j) {
            *(unsigned*)&lds[(d0 + j) * QS + c0] =
                pk(((const float*)&a0)[j], ((const float*)&b0)[j]);
            *(unsigned*)&lds[(d0 + 4 + j) * QS + c0] =
                pk(((const float*)&a1)[j], ((const float*)&b1)[j]);
        }
        __syncthreads();
        // write out: d = tid>>2, cs = tid&3 -> 32B contiguous per thread
        const int d = tid >> 2, cs = tid & 3;
        f16x8 r0 = *(const f16x8*)&lds[d * QS + cs * 16];
        f16x8 r1 = *(const f16x8*)&lds[d * QS + cs * 16 + 8];
        f16* dst = wsV + ((((size_t)bh * 32 + t) << 6) + d) * 64 + cs * 16;
        *(f16x8*)(dst) = r0;
        *(f16x8*)(dst + 8) = r1;
    }
}

// ---------------- main kernel ----------------
__global__ __launch_bounds__(1024, 8)
void stk_attn_mfma(const float* __restrict__ qg, const f16* __restrict__ wsK,
                   const f16* __restrict__ wsV, const float* __restrict__ sg,
                   float* __restrict__ og) {
    extern __shared__ f16 smem[];

    const int tid  = threadIdx.x;
    const int wv   = tid >> 6;        // 0..15
    const int grp  = wv >> 3;         // key-group 0/1
    const int wv7  = wv & 7;          // wave within group
    const int lane = tid & 63;
    const int l15  = lane & 15;
    const int q4   = lane >> 4;
    const int tg   = (wv7 << 6) | lane;  // tid within group, 0..511
    const int bh   = blockIdx.x & 31; // XCD swizzle: head h -> blocks h+32j -> XCD h%8
    const int q0   = (blockIdx.x >> 5) * ROWS;
    const float scale2 = sg[0] * C2;  // fold 2*log2e: acc = 2L*log2e

    const float* qb = qg + (size_t)bh * N_CTX * DH;
    float*       ob = og + (size_t)bh * N_CTX * DH;
    const f16* wsKh = wsK + ((size_t)bh << 17);   // *131072
    const f16* wsVh = wsV + ((size_t)bh << 17);
    const int T0 = grp * NKT_G;       // group's first tile (of 32 per head)

    // ---- Q fragments direct from global: row q0 + wv7*16 + l15 ----
    f16x8 aq[2];
    {
        const float* qrow = qb + (size_t)(q0 + wv7 * 16 + l15) * DH;
        #pragma unroll
        for (int kc = 0; kc < 2; ++kc) {
            float4 a0 = *(const float4*)&qrow[kc * 32 + q4 * 8];
            float4 a1 = *(const float4*)&qrow[kc * 32 + q4 * 8 + 4];
            union { f16x8 h; unsigned u[4]; } A;
            A.u[0] = pk(a0.x * scale2, a0.y * scale2);
            A.u[1] = pk(a0.z * scale2, a0.w * scale2);
            A.u[2] = pk(a1.x * scale2, a1.y * scale2);
            A.u[3] = pk(a1.z * scale2, a1.w * scale2);
            aq[kc] = A.h;
        }
    }

    // group-private LDS bases
    f16* const ksBase = smem + grp * (2 * KSB);             // 2 tiles
    f16* const vtBase = smem + 2 * (2 * KSB) + grp * (2 * KSB);
    float* const sred = (float*)(smem + 4 * (2 * KSB));     // 512 floats
    float* const obuf = (float*)smem;                       // epilogue reuse

    const int sofs = tg * 8;                          // ws tile read offset (f16)
    const int wofs = (tg >> 3) * QS + (tg & 7) * 8;   // LDS b128 write offset

    const f16* const ks_r = ksBase + l15 * QS + q4 * 8;   // QK^T A-frag: K row l15
    const f16* const ksrB = vtBase + l15 * QS + q4 * 8;   // pass-1 alt buffer
    const f16* const vt_r = vtBase + l15 * QS + q4 * 16;  // PV A-frags: 16 f16

    // ===== PASS 1: s1 = sum_k exp(2L); 2-tile super-buffers via idle Vt =====
    float s1 = 0.f;
    f16x8 kr2[2];
    // prologue: super-tile 0 -> ksBase region; load super-tile 1
    kr2[0] = *(const f16x8*)&wsKh[(size_t)T0 * 4096 + sofs];
    kr2[1] = *(const f16x8*)&wsKh[(size_t)(T0 + 1) * 4096 + sofs];
    *(f16x8*)&ksBase[wofs] = kr2[0];
    *(f16x8*)&ksBase[KSB + wofs] = kr2[1];
    kr2[0] = *(const f16x8*)&wsKh[(size_t)(T0 + 2) * 4096 + sofs];
    kr2[1] = *(const f16x8*)&wsKh[(size_t)(T0 + 3) * 4096 + sofs];
    __syncthreads();

    for (int st = 0; st < 8; ++st) {
        f16* const nxtb = (st & 1) ? ksBase : vtBase;
        const f16* const crd = (st & 1) ? ksrB : ks_r;
        // write super-tile st+1 into the other super-buffer
        *(f16x8*)&nxtb[wofs] = kr2[0];
        *(f16x8*)&nxtb[KSB + wofs] = kr2[1];
        {   // prefetch super-tile st+2 (clamped)
            int tn = (st + 2 < 8) ? st + 2 : 7;
            kr2[0] = *(const f16x8*)&wsKh[(size_t)(T0 + 2 * tn) * 4096 + sofs];
            kr2[1] = *(const f16x8*)&wsKh[(size_t)(T0 + 2 * tn + 1) * 4096 + sofs];
        }
        __builtin_amdgcn_s_setprio(1);
        #pragma unroll
        for (int kgi = 0; kgi < 8; ++kgi) {
            f16x8 b0 = *(const f16x8*)&crd[kgi * 16 * QS];
            f16x8 b1 = *(const f16x8*)&crd[kgi * 16 * QS + 32];
            f32x4 acc = {0.f, 0.f, 0.f, 0.f};
            acc = MFMA32(b0, aq[0], acc);   // swapped: C[key][q], lane q = l15
            acc = MFMA32(b1, aq[1], acc);
            s1 += (EXP2(acc[0]) + EXP2(acc[1])) + (EXP2(acc[2]) + EXP2(acc[3]));
        }
        __builtin_amdgcn_s_setprio(0);
        __syncthreads();
    }
    // reduce across q4 partitions, then across key-groups via sred
    s1 += __shfl_xor(s1, 16, 64);
    s1 += __shfl_xor(s1, 32, 64);
    if (lane < 16) sred[(grp << 7) + (wv7 << 4) + lane] = s1;
    __syncthreads();
    s1 += sred[((grp ^ 1) << 7) + (wv7 << 4) + l15];
    const float inv1 = 0.5f / s1;    // e2 = exp2((acc*e1) * 0.5/s1)  [acc = 2L*log2e]

    // =============== PASS 2: e2, O^T += V^T P^T, l2 via ones-MFMA ===============
    f32x4 O[4];
    #pragma unroll
    for (int dt = 0; dt < 4; ++dt) O[dt] = (f32x4){0.f, 0.f, 0.f, 0.f};
    f32x4 Oe = {0.f, 0.f, 0.f, 0.f};
    const f16x4 ones = {(f16)1.f, (f16)1.f, (f16)1.f, (f16)1.f};

    f16* const ks_w = ksBase;
    f16* const vt_w = vtBase;
    f16x8 krh, vrh;
    krh = *(const f16x8*)&wsKh[(size_t)T0 * 4096 + sofs];
    vrh = *(const f16x8*)&wsVh[(size_t)T0 * 4096 + sofs];
    __syncthreads();   // pass-1 reads of vtBase done before restage
    *(f16x8*)&ks_w[wofs] = krh;
    *(f16x8*)&vt_w[wofs] = vrh;
    krh = *(const f16x8*)&wsKh[(size_t)(T0 + 1) * 4096 + sofs];
    vrh = *(const f16x8*)&wsVh[(size_t)(T0 + 1) * 4096 + sofs];
    __syncthreads();

    for (int kt = 0; kt < NKT_G; ++kt) {
        const int cur = (kt & 1) * KSB, nxt = KSB - cur;
        *(f16x8*)&ks_w[nxt + wofs] = krh;
        *(f16x8*)&vt_w[nxt + wofs] = vrh;
        { int tn = (kt + 2 < NKT_G) ? kt + 2 : NKT_G - 1;
          krh = *(const f16x8*)&wsKh[(size_t)(T0 + tn) * 4096 + sofs];
          vrh = *(const f16x8*)&wsVh[(size_t)(T0 + tn) * 4096 + sofs]; }
        // per kgi-PAIR: softmax(2p), softmax(2p+1) -> PV(pair p) via b128 V-frags
        __builtin_amdgcn_s_setprio(1);
        #pragma unroll
        for (int p = 0; p < 2; ++p) {
            f16x4 pfr[2];
            #pragma unroll
            for (int h = 0; h < 2; ++h) {
                const int kgi = p * 2 + h;
                f16x8 b0 = *(const f16x8*)&ks_r[cur + kgi * 16 * QS];
                f16x8 b1 = *(const f16x8*)&ks_r[cur + kgi * 16 * QS + 32];
                f32x4 acc = {0.f, 0.f, 0.f, 0.f};
                acc = MFMA32(b0, aq[0], acc);
                acc = MFMA32(b1, aq[1], acc);
                float e2r[4];
                #pragma unroll
                for (int r = 0; r < 4; ++r) {
                    float a  = acc[r];
                    float e1 = EXP2(a);
                    e2r[r] = EXP2((a * e1) * inv1);
                }
                union { f16x4 hh; unsigned u[2]; } P;
                P.u[0] = pk(e2r[0], e2r[1]);
                P.u[1] = pk(e2r[2], e2r[3]);
                pfr[h] = P.hh;
                Oe = MFMA16(ones, pfr[h], Oe);
            }
            #pragma unroll
            for (int dt = 0; dt < 4; ++dt) {
                f16x8 av = *(const f16x8*)&vt_r[cur + dt * 16 * QS + p * 8];
                f16x4 alo = __builtin_shufflevector(av, av, 0, 1, 2, 3);
                f16x4 ahi = __builtin_shufflevector(av, av, 4, 5, 6, 7);
                O[dt] = MFMA16(alo, pfr[0], O[dt]);
                O[dt] = MFMA16(ahi, pfr[1], O[dt]);
            }
        }
        __builtin_amdgcn_s_setprio(0);
        __syncthreads();   // swap: protects Ks/Vt cur<->nxt
    }

    // ---- cross-group merge of O/Oe via dead Ks/Vt LDS; group 0 writes ----
    const int rec = tg * 20;   // 20 f32/thread, 16B-aligned (80 B)
    if (grp) {
        #pragma unroll
        for (int dt = 0; dt < 4; ++dt)
            *(f32x4*)&obuf[rec + dt * 4] = O[dt];
        obuf[rec + 16] = Oe[0];
    }
    __syncthreads();
    if (!grp) {
        #pragma unroll
        for (int dt = 0; dt < 4; ++dt)
            O[dt] += *(const f32x4*)&obuf[rec + dt * 4];
        const float invl2 = 1.0f / (Oe[0] + obuf[rec + 16]);
        const size_t orow = (size_t)(q0 + wv7 * 16 + l15) * DH;
        #pragma unroll
        for (int dt = 0; dt < 4; ++dt) {
            float4 o;
            o.x = O[dt][0] * invl2;
            o.y = O[dt][1] * invl2;
            o.z = O[dt][2] * invl2;
            o.w = O[dt][3] * invl2;
            *(float4*)&ob[orow + dt * 16 + q4 * 4] = o;
        }
    }
}

extern "C" void kernel_launch(void* const* d_in, const int* in_sizes, int n_in,
                              void* d_out, int out_size, void* d_ws, size_t ws_size,
                              hipStream_t stream) {
    const float* q = (const float*)d_in[0];
    const float* k = (const float*)d_in[1];
    const float* v = (const float*)d_in[2];
    const float* s = (const float*)d_in[3];
    float* out = (float*)d_out;
    f16* wsK = (f16*)d_ws;                       // 8 MB
    f16* wsV = wsK + (size_t)32 * N_CTX * DH;    // 8 MB
    stk_prep<<<dim3(3072), dim3(256), 0, stream>>>(k, v, wsK, wsV);
    dim3 grid(32 * 16);   // bh = blockIdx&31 (XCD swizzle), q-tile = blockIdx>>5
    stk_attn_mfma<<<grid, 1024, SMEM_BYTES, stream>>>(q, wsK, wsV, s, out);
}